// Round 4
// baseline (425.593 us; speedup 1.0000x reference)
//
#include <hip/hip_runtime.h>

// ---- filter / neuron constants (double, matching the Python reference) ----
#define EMD 0.8824969025845955      // exp(-1/8)
#define ESD 0.6065306597126334      // exp(-1/2)
#define A1C ((float)(EMD + ESD))                    // y[t-1] coeff
#define A2C ((float)(-(EMD * ESD)))                 // y[t-2] coeff
#define BC  ((float)((8.0 / 6.0) * (EMD - ESD)))    // x[t] coeff (ETA=8/6)
#define EMF ((float)EMD)                            // reset decay

// B=64, T=300. Layers: 300 -> 500 -> 200 -> 500 -> 300.
//
// Exactness contract (absmax 0.0 through r8): reference currents are a
// SEQUENTIAL ascending-i fp32 fold of W[o,i]*s[i]; spikes are exactly 0/1.
// Skipping s==0 terms is bitwise-neutral; set bits processed ascending is
// the SAME add sequence. r9: spikes travel as packed u32 masks (bit j of
// word w = neuron w*32+j, exactly the __ballot bits r8 computed on the fly);
// the walk (ascending bits within word, words ascending) is unchanged ->
// identical fold per (t,o).
//
// History: r6 (VALU bit-extract) 105->131us: >1 VALU op per accumulated
// float loses. r7 (dense reg-weight fmac) 8x worse: VGPR spill + dense work
// floor >= sparse measured. r8 (16KB LDS, spike prefetch) 105->77us, occ
// 36->50%. r9: masks end-to-end; spmm S-loads+ballots -> one scalar load.

// ---------------------------------------------------------------------------
// Fused weight transposes: z selects one of 4 W[O,K] -> Wt[K,O] jobs.
// ---------------------------------------------------------------------------
__global__ __launch_bounds__(256) void transpose_w4(
    const float* __restrict__ W1, float* __restrict__ D1,
    const float* __restrict__ W2, float* __restrict__ D2,
    const float* __restrict__ W3, float* __restrict__ D3,
    const float* __restrict__ W4, float* __restrict__ D4)
{
    __shared__ float tile[32][33];
    int R, C; const float* S; float* D;
    switch (blockIdx.z) {
        case 0:  S = W1; D = D1; R = 500; C = 300; break;
        case 1:  S = W2; D = D2; R = 200; C = 500; break;
        case 2:  S = W3; D = D3; R = 500; C = 200; break;
        default: S = W4; D = D4; R = 300; C = 500; break;
    }
    const int c0 = blockIdx.x * 32;
    const int r0 = blockIdx.y * 32;
    if (c0 >= C || r0 >= R) return;       // block-uniform, before barrier
    const int tx = threadIdx.x;           // 0..31
    const int ty = threadIdx.y;           // 0..7
#pragma unroll
    for (int s = 0; s < 4; s++) {
        const int r = r0 + ty + 8 * s;
        const int c = c0 + tx;
        if (r < R && c < C) tile[ty + 8 * s][tx] = S[(size_t)r * C + c];
    }
    __syncthreads();
#pragma unroll
    for (int s = 0; s < 4; s++) {
        const int c = c0 + ty + 8 * s;
        const int r = r0 + tx;
        if (c < C && r < R) D[(size_t)c * R + r] = tile[tx][ty + 8 * s];
    }
}

// ---------------------------------------------------------------------------
// Generic batched transpose: src [Bt][R][C] -> dst [Bt][C][R]  (final outputs)
// ---------------------------------------------------------------------------
__global__ __launch_bounds__(256) void transpose_rc(
    const float* __restrict__ src, float* __restrict__ dst, int R, int C)
{
    __shared__ float tile[32][33];
    const int c0 = blockIdx.x * 32;
    const int r0 = blockIdx.y * 32;
    const int b  = blockIdx.z;
    const float* S = src + (size_t)b * R * C;
    float* D = dst + (size_t)b * R * C;
    const int tx = threadIdx.x;
    const int ty = threadIdx.y;
#pragma unroll
    for (int s = 0; s < 4; s++) {
        const int r = r0 + ty + 8 * s;
        const int c = c0 + tx;
        if (r < R && c < C) tile[ty + 8 * s][tx] = S[(size_t)r * C + c];
    }
    __syncthreads();
#pragma unroll
    for (int s = 0; s < 4; s++) {
        const int c = c0 + ty + 8 * s;
        const int r = r0 + tx;
        if (c < C && r < R) D[(size_t)c * R + r] = tile[tx][ty + 8 * s];
    }
}

// ---------------------------------------------------------------------------
// Input transpose+pack: src [B][R=K][C=T] binary floats -> masks
// M[b][t][kw] (MW u32 per row), bit j of word kw = (src[b][kw*32+j][t] != 0).
// Never materializes the float transpose.
// ---------------------------------------------------------------------------
__global__ __launch_bounds__(256) void transpose_pack(
    const float* __restrict__ src, unsigned* __restrict__ M,
    int R, int C, int MW)
{
    __shared__ float tile[32][33];
    const int c0 = blockIdx.x * 32;       // t block
    const int r0 = blockIdx.y * 32;       // k block (one mask word)
    const int b  = blockIdx.z;
    const float* S = src + (size_t)b * R * C;
    const int tx = threadIdx.x;           // 0..31
    const int ty = threadIdx.y;           // 0..7
#pragma unroll
    for (int s = 0; s < 4; s++) {
        const int r = r0 + ty + 8 * s;
        const int c = c0 + tx;
        tile[ty + 8 * s][tx] = (r < R && c < C) ? S[(size_t)r * C + c] : 0.0f;
    }
    __syncthreads();
    // wave = lanes (tx, ty) with ty pair (2w, 2w+1); half 0 = lanes 0-31.
    const int wv   = ty >> 1;             // 0..3
    const int half = ty & 1;
#pragma unroll
    for (int s = 0; s < 4; s++) {
        const int tl = wv * 8 + s * 2 + half;          // 0..31, both halves
        const float v = tile[tx][tl];                  // OOB pre-zeroed
        const unsigned long long mb = __ballot(v != 0.0f);
        const int t = c0 + tl;
        if (tx == 0 && t < C) {
            const unsigned w32 = half ? (unsigned)(mb >> 32) : (unsigned)mb;
            M[((size_t)b * C + t) * MW + (r0 >> 5)] = w32;
        }
    }
}

// ---------------------------------------------------------------------------
// Sparse spike GEMM: C[b,t,o] = sum_i Wt[i,o] * bit(M[b,t,i]), skipping 0s.
// M: packed masks [B,T,MW], Wt: [K,O], C: [B,T,O].
// Block: 256 thr (4 waves), o-chunk 128 (2 o's/lane), t-chunk 32 (8 t/wave),
// K staged in 32-row LDS chunks (16 KB), weights register-prefetched one
// chunk ahead. Spike masks arrive as ONE wave-uniform scalar u32 load per
// (t, chunk) -- r8's 8 vector loads + 8 ballots per chunk/wave are gone.
// Walk: scalar ctz on wave-uniform masks, 4/2/1-wide ds_read_b64 groups,
// 2 v_add per set bit (the instruction floor).
// ---------------------------------------------------------------------------
#define KG  32
#define OCN 128
#define TCN 32

// walk one wave-uniform 32-bit mask into one float2 accumulator
#define WALK32(mw, accu)                                                      \
    {                                                                         \
        unsigned int mask_ = (mw);                                            \
        int n_ = __popc(mask_);                                               \
        float ax_ = (accu).x, ay_ = (accu).y;                                 \
        while (n_ >= 4) {                                                     \
            const int j0_ = __builtin_ctz(mask_); mask_ &= mask_ - 1u;        \
            const int j1_ = __builtin_ctz(mask_); mask_ &= mask_ - 1u;        \
            const int j2_ = __builtin_ctz(mask_); mask_ &= mask_ - 1u;        \
            const int j3_ = __builtin_ctz(mask_); mask_ &= mask_ - 1u;        \
            const float2 w0_ = *(const float2*)(&wlane[j0_ * OCN]);           \
            const float2 w1_ = *(const float2*)(&wlane[j1_ * OCN]);           \
            const float2 w2_ = *(const float2*)(&wlane[j2_ * OCN]);           \
            const float2 w3_ = *(const float2*)(&wlane[j3_ * OCN]);           \
            ax_ += w0_.x; ay_ += w0_.y;                                       \
            ax_ += w1_.x; ay_ += w1_.y;                                       \
            ax_ += w2_.x; ay_ += w2_.y;                                       \
            ax_ += w3_.x; ay_ += w3_.y;                                       \
            n_ -= 4;                                                          \
        }                                                                     \
        if (n_ >= 2) {                                                        \
            const int j0_ = __builtin_ctz(mask_); mask_ &= mask_ - 1u;        \
            const int j1_ = __builtin_ctz(mask_); mask_ &= mask_ - 1u;        \
            const float2 w0_ = *(const float2*)(&wlane[j0_ * OCN]);           \
            const float2 w1_ = *(const float2*)(&wlane[j1_ * OCN]);           \
            ax_ += w0_.x; ay_ += w0_.y;                                       \
            ax_ += w1_.x; ay_ += w1_.y;                                       \
            n_ -= 2;                                                          \
        }                                                                     \
        if (n_ > 0) {                                                         \
            const int j0_ = __builtin_ctz(mask_);                             \
            const float2 w0_ = *(const float2*)(&wlane[j0_ * OCN]);           \
            ax_ += w0_.x; ay_ += w0_.y;                                       \
        }                                                                     \
        (accu).x = ax_; (accu).y = ay_;                                       \
    }

__global__ __launch_bounds__(256, 8) void spmm_snn(
    const unsigned* __restrict__ M, const float* __restrict__ Wt,
    float* __restrict__ C, int K, int O, int T, int MW)
{
    __shared__ float Wls[KG * OCN];   // 16 KB
    const int tid  = threadIdx.x;
    const int lane = tid & 63;
    const int wv   = __builtin_amdgcn_readfirstlane(tid >> 6);   // SGPR 0..3
    const int oc   = blockIdx.x * OCN;
    const int t0   = blockIdx.y * TCN;
    const int b    = blockIdx.z;

    const unsigned* Mb = M + (size_t)b * T * MW;
    float* Cb = C + (size_t)b * T * O;

    // weight staging: 32 rows x 128 cols = 16 KB = 256 thr x float4 x 4 iters
    const int srow  = tid >> 5;        // base row (stride 8 over r)
    const int scol4 = (tid & 31) * 4;

    float2 acc[8];
#pragma unroll
    for (int u = 0; u < 8; u++) acc[u] = make_float2(0.f, 0.f);

    const int nkc = (K + KG - 1) / KG;
    float4 wpf[4];

#define LOADW(kc)                                                              \
    {                                                                          \
        const int kb_ = (kc) * KG;                                             \
        _Pragma("unroll")                                                      \
        for (int r = 0; r < 4; r++) {                                          \
            const int k = kb_ + srow + r * 8;                                  \
            const int o = oc + scol4;                                          \
            float4 w = make_float4(0.f, 0.f, 0.f, 0.f);                        \
            if (k < K && o + 3 < O)                                            \
                w = *reinterpret_cast<const float4*>(&Wt[(size_t)k * O + o]);  \
            wpf[r] = w;                                                        \
        }                                                                      \
    }

#define STOREW()                                                               \
    {                                                                          \
        _Pragma("unroll")                                                      \
        for (int r = 0; r < 4; r++)                                            \
            *reinterpret_cast<float4*>(&Wls[(srow + r * 8) * OCN + scol4]) = wpf[r]; \
    }

    // wave-uniform mask loads (scalar pipe), prefetched one chunk ahead
    unsigned mk[8], mkn[8];
#define LOADM(kc, dst)                                                         \
    {                                                                          \
        _Pragma("unroll")                                                      \
        for (int u = 0; u < 8; u++) {                                          \
            const int t = t0 + u * 4 + wv;                                     \
            dst[u] = (t < T) ? Mb[(size_t)t * MW + (kc)] : 0u;                 \
        }                                                                      \
    }

    LOADW(0)
    LOADM(0, mk)
    STOREW()
    __syncthreads();

    // per-lane LDS base: row j's float2 for this lane at float offset j*OCN
    const float* wlane = &Wls[lane * 2];

    for (int kc = 0; kc < nkc; kc++) {
        if (kc + 1 < nkc) {
            LOADW(kc + 1)          // global->reg, lands during the walk
            LOADM(kc + 1, mkn)
        }

#pragma unroll
        for (int u = 0; u < 8; u++) {
            WALK32(mk[u], acc[u])                  // t = t0 + u*4 + wv
        }

        if (kc + 1 < nkc) {
            __syncthreads();       // all waves done reading Wls
            STOREW()
#pragma unroll
            for (int u = 0; u < 8; u++) mk[u] = mkn[u];
            __syncthreads();       // Wls chunk kc+1 visible
        }
    }

#pragma unroll
    for (int u = 0; u < 8; u++) {
        const int t = t0 + u * 4 + wv;
        const int o = oc + lane * 2;
        if (t < T && o + 1 < O)               // O even -> pair all-or-nothing
            *reinterpret_cast<float2*>(&Cb[(size_t)t * O + o]) = acc[u];
    }
}

// ---------------------------------------------------------------------------
// LIF (layers 1-3): currents C[b,t,o] -> packed spike masks M[b][t][MW].
// One wave per (b, 64-o-chunk); per t: LIF step + __ballot -> one 8B store
// from lane 0 (bit j of word = o = word*32+j, ascending -- same bits r8's
// spmm balloted from float spikes). Float spikes never materialize.
// ---------------------------------------------------------------------------
#define LIF_STEP_S(xval, sval)                                                 \
    {                                                                          \
        const float y = A1 * y1 + A2 * y2 + Bc * (xval); y2 = y1; y1 = y;      \
        const float v = y + bi + r;                                            \
        sval = (v >= 1.0f) ? 1.0f : 0.0f;                                      \
        r = r * EMF - sval;                                                    \
    }

__global__ __launch_bounds__(64) void lif_pack(
    const float* __restrict__ C, unsigned* __restrict__ M,
    const float* __restrict__ bias,
    const float* __restrict__ a1p, const float* __restrict__ a2p,
    const float* __restrict__ bp, int O, int MW)
{
    const int lane = threadIdx.x;
    const int o = blockIdx.x * 64 + lane;
    const int b = blockIdx.y;
    if (o >= O) return;                    // exited lanes ballot as 0
    const float A1 = a1p[0], A2 = a2p[0], Bc = bp[0];
    const float bi = bias[o];
    const float* col = C + (size_t)b * 300 * O + o;
    // u64 view of this b's mask rows; our word pair = blockIdx.x (MW even)
    unsigned long long* Mp =
        (unsigned long long*)(M + (size_t)b * 300 * MW);
    const int pair = blockIdx.x;
    const int hw   = MW >> 1;

    float pf[8];
#pragma unroll
    for (int u = 0; u < 8; u++) pf[u] = col[(size_t)u * O];

    float y1 = 0.f, y2 = 0.f, r = 0.f;
    for (int blk = 0; blk < 37; blk++) {       // t = 0..295
#pragma unroll
        for (int u = 0; u < 8; u++) {
            const int t = blk * 8 + u;
            const float x = pf[u];
            if (t + 8 < 300) pf[u] = col[(size_t)(t + 8) * O];
            float s;
            LIF_STEP_S(x, s)
            const unsigned long long mb = __ballot(s != 0.0f);
            if (lane == 0) Mp[(size_t)t * hw + pair] = mb;
        }
    }
#pragma unroll
    for (int u = 0; u < 4; u++) {              // t = 296..299
        const float x = pf[u];
        float s;
        LIF_STEP_S(x, s)
        const unsigned long long mb = __ballot(s != 0.0f);
        if (lane == 0) Mp[(size_t)(296 + u) * hw + pair] = mb;
    }
}

// ---------------------------------------------------------------------------
// Layer-4 LIF + fixed output dual-exp IIR. C: currents->spikes (in place),
// F: filtered output. Both [B,T,O], O=300. (Spikes ARE an output here.)
// ---------------------------------------------------------------------------
__global__ __launch_bounds__(64) void lif4_t(
    float* __restrict__ C, float* __restrict__ F,
    const float* __restrict__ bias,
    const float* __restrict__ a1p, const float* __restrict__ a2p,
    const float* __restrict__ bp, int O)
{
    const int o = blockIdx.x * 64 + threadIdx.x;
    const int b = blockIdx.y;
    if (o >= O) return;
    const float A1 = a1p[0], A2 = a2p[0], Bc = bp[0];
    const float bi = bias[o];
    float* col  = C + (size_t)b * 300 * O + o;
    float* fcol = F + (size_t)b * 300 * O + o;

    float pf[8];
#pragma unroll
    for (int u = 0; u < 8; u++) pf[u] = col[(size_t)u * O];

    float y1 = 0.f, y2 = 0.f, r = 0.f;
    float z1 = 0.f, z2 = 0.f;
    for (int blk = 0; blk < 37; blk++) {
#pragma unroll
        for (int u = 0; u < 8; u++) {
            const int t = blk * 8 + u;
            const float x = pf[u];
            if (t + 8 < 300) pf[u] = col[(size_t)(t + 8) * O];
            float s;
            LIF_STEP_S(x, s)
            const float z = A1C * z1 + A2C * z2 + BC * s; z2 = z1; z1 = z;
            col[(size_t)t * O]  = s;
            fcol[(size_t)t * O] = z;
        }
    }
#pragma unroll
    for (int u = 0; u < 4; u++) {
        const int t = 296 + u;
        const float x = pf[u];
        float s;
        LIF_STEP_S(x, s)
        const float z = A1C * z1 + A2C * z2 + BC * s; z2 = z1; z1 = z;
        col[(size_t)t * O]  = s;
        fcol[(size_t)t * O] = z;
    }
}

// ---------------------------------------------------------------------------
extern "C" void kernel_launch(void* const* d_in, const int* in_sizes, int n_in,
                              void* d_out, int out_size, void* d_ws, size_t ws_size,
                              hipStream_t stream)
{
    const float* inputs = (const float*)d_in[0];           // [64,300,300] binary
    const float* a1_1 = (const float*)d_in[1];
    const float* a2_1 = (const float*)d_in[2];
    const float* b_1  = (const float*)d_in[3];
    const float* W1   = (const float*)d_in[4];             // [500,300]
    const float* bias1= (const float*)d_in[5];
    const float* a1_2 = (const float*)d_in[6];
    const float* a2_2 = (const float*)d_in[7];
    const float* b_2  = (const float*)d_in[8];
    const float* W2   = (const float*)d_in[9];             // [200,500]
    const float* bias2= (const float*)d_in[10];
    const float* a1_3 = (const float*)d_in[11];
    const float* a2_3 = (const float*)d_in[12];
    const float* b_3  = (const float*)d_in[13];
    const float* W3   = (const float*)d_in[14];            // [500,200]
    const float* bias3= (const float*)d_in[15];
    const float* a1_4 = (const float*)d_in[16];
    const float* a2_4 = (const float*)d_in[17];
    const float* b_4  = (const float*)d_in[18];
    const float* W4   = (const float*)d_in[19];            // [300,500]
    const float* bias4= (const float*)d_in[20];

    const int B = 64, T = 300;

    // Workspace (proven size 53.76 MB): c1 = 9.6M floats, c2 = 3.84M floats.
    float* ws = (float*)d_ws;
    float* c1 = ws;                 // [B,T,500] currents; later filt_tmp
    float* c2 = ws + 9600000;       // [B,T,200] currents

    // d_out regions double as scratch until the final transposes:
    // region1 [0..5.76M): Wt1..4 + packed masks, later final s4 [B,O,T]
    // region2 [5.76M..11.52M): c4/s4_tmp [B,T,300], later final filt
    float* out = (float*)d_out;
    float* reg1 = out;
    float* reg2 = out + 5760000;
    float* Wt1 = reg1;              // [300,500] = 150000
    float* Wt2 = reg1 + 150000;     // [500,200] = 100000
    float* Wt3 = reg1 + 250000;     // [200,500] = 100000
    float* Wt4 = reg1 + 350000;     // [500,300] = 150000
    // masks (u32), 8B-aligned, all dead before final transposes:
    unsigned* m0 = (unsigned*)(reg1 + 500000);   // [64,300,10] = 192000
    unsigned* m1 = (unsigned*)(reg1 + 692000);   // [64,300,16] = 307200
    unsigned* m2 = (unsigned*)(reg1 + 999200);   // [64,300, 8] = 153600
    unsigned* m3 = (unsigned*)(reg1 + 1152800);  // [64,300,16] = 307200

    const dim3 tb(32, 8);

    // Weight transposes (fused) + input transpose-pack
    transpose_w4<<<dim3(16, 16, 4), tb, 0, stream>>>(W1, Wt1, W2, Wt2,
                                                     W3, Wt3, W4, Wt4);
    transpose_pack<<<dim3(10, 10, B), tb, 0, stream>>>(inputs, m0, 300, 300, 10);

    // Layer 1: 300 -> 500
    spmm_snn<<<dim3(4, 10, B), 256, 0, stream>>>(m0, Wt1, c1, 300, 500, T, 10);
    lif_pack<<<dim3(8, B), 64, 0, stream>>>(c1, m1, bias1, a1_1, a2_1, b_1, 500, 16);
    // Layer 2: 500 -> 200
    spmm_snn<<<dim3(2, 10, B), 256, 0, stream>>>(m1, Wt2, c2, 500, 200, T, 16);
    lif_pack<<<dim3(4, B), 64, 0, stream>>>(c2, m2, bias2, a1_2, a2_2, b_2, 200, 8);
    // Layer 3: 200 -> 500 (currents back into c1)
    spmm_snn<<<dim3(4, 10, B), 256, 0, stream>>>(m2, Wt3, c1, 200, 500, T, 8);
    lif_pack<<<dim3(8, B), 64, 0, stream>>>(c1, m3, bias3, a1_3, a2_3, b_3, 500, 16);
    // Layer 4: 500 -> 300 into reg2; LIF+filter, filt_tmp -> c1
    spmm_snn<<<dim3(3, 10, B), 256, 0, stream>>>(m3, Wt4, reg2, 500, 300, T, 16);
    lif4_t<<<dim3(5, B), 64, 0, stream>>>(reg2, c1, bias4, a1_4, a2_4, b_4, 300);

    // Final transposes [B,T,O] -> [B,O,T]: s4 first (frees reg2), then filt.
    transpose_rc<<<dim3(10, 10, B), tb, 0, stream>>>(reg2, reg1, 300, 300);
    transpose_rc<<<dim3(10, 10, B), tb, 0, stream>>>(c1, reg2, 300, 300);
}